// Round 19
// baseline (23.374 us; speedup 1.0000x reference)
//
#include <hip/hip_runtime.h>
#include <math.h>

#define NB 1024
#define IC 3
#define HW 32
#define GCH 16
#define ECH 32
#define NE 8
#define NC 100

#define CS 38            // plane (ci) stride in texels
#define RS2 114          // row stride (3 planes interleaved per row)
#define NTX 3876         // 34 rows * 114

typedef __attribute__((ext_vector_type(8))) short bf16x8;
typedef __attribute__((ext_vector_type(4))) int   int4v;
typedef __attribute__((ext_vector_type(4))) float f32x4;

__device__ inline short f2bf(float f) {   // RNE fp32->bf16
    unsigned u = __float_as_uint(f);
    unsigned r = (u + 0x7FFF + ((u >> 16) & 1)) >> 16;
    return (short)r;
}
__device__ inline float bf2f(short h) {
    return __uint_as_float(((unsigned)(unsigned short)h) << 16);
}

// TWO samples per block (512 blocks): each m-iteration carries two fully
// independent ds_read->v_perm->MFMA chains (sample A and B) -> 2x ILP per
// wave replaces the halved waves/CU, and all barriers + reduce + softmax +
// tail serial sections amortize over 2 samples. r15-r18 evidence: the
// kernel is dependency-latency + serial-section bound, not pipe-bound.
// Layout/k-map identical to r18 (wave-uniform immediate tap offsets).
// Gate hi/lo split (argmax-exact); expert hi-only (absmax 0.0078).
__global__ __launch_bounds__(256) void moe_fused_kernel(
    const float* __restrict__ x,     // [1024,3,32,32]
    const float* __restrict__ gcw,   // [16,3,3,3]
    const float* __restrict__ gcb,   // [16]
    const float* __restrict__ glw,   // [8,16]
    const float* __restrict__ glb,   // [8]
    const float* __restrict__ ecw,   // [8,32,3,3,3]
    const float* __restrict__ ecb,   // [8,32]
    const float* __restrict__ elw,   // [8,100,32]
    const float* __restrict__ elb,   // [8,100]
    float* __restrict__ out_final,   // [1024,100]
    float* __restrict__ out_w)       // [1024,8]
{
    __shared__ __align__(16) int xil[2 * NTX];   // 31 KB, two images
    __shared__ float red2[4][64];
    __shared__ float pg[2][GCH];
    __shared__ float pe[2][ECH];
    __shared__ int s_best[2];

    const int t = threadIdx.x;
    const int bA = 2 * blockIdx.x;
    const int bB = bA + 1;
    const int lane = t & 63;
    const int wid = t >> 6;
    const int r15 = lane & 15;
    const int kg = lane >> 4;
    const bool k3 = (kg == 3);
    const int kgoff = k3 ? 0 : kg * CS;

    // ---- zero both images ----
    for (int i = t; i < (2 * NTX) / 4; i += 256)
        ((int4*)xil)[i] = make_int4(0, 0, 0, 0);

    // ---- gate B-fragments (hi+lo), shared across samples ----
    bf16x8 gbh, gbl;
    #pragma unroll
    for (int r = 0; r < 8; ++r) {
        float w = 0.f;
        if (kg < 3) w = gcw[r15 * 27 + kg * 9 + r];
        else if (r < 3) w = gcw[r15 * 27 + r * 9 + 8];
        short h = f2bf(w);
        gbh[r] = h;
        gbl[r] = f2bf(w - bf2f(h));
    }
    const float gb = gcb[r15];

    __syncthreads();

    // ---- stage both samples -> interleaved texels ----
    const float* xbA = x + (size_t)bA * (IC * HW * HW);
    const float* xbB = x + (size_t)bB * (IC * HW * HW);
    #pragma unroll
    for (int i6 = 0; i6 < 6; ++i6) {
        int i = t + i6 * 256;
        int smp = (i >= 768);
        int ii = i - (smp ? 768 : 0);
        float4 v = smp ? ((const float4*)xbB)[ii] : ((const float4*)xbA)[ii];
        int ci = ii >> 8, rem = ii & 255, row = rem >> 3, x4 = (rem & 7) << 2;
        int T = (smp ? NTX : 0) + (row + 1) * RS2 + ci * CS + x4 + 2;
        short h0 = f2bf(v.x), h1 = f2bf(v.y), h2 = f2bf(v.z), h3 = f2bf(v.w);
        int t0 = (unsigned short)h0 | ((unsigned)(unsigned short)f2bf(v.x - bf2f(h0)) << 16);
        int t1 = (unsigned short)h1 | ((unsigned)(unsigned short)f2bf(v.y - bf2f(h1)) << 16);
        int t2 = (unsigned short)h2 | ((unsigned)(unsigned short)f2bf(v.z - bf2f(h2)) << 16);
        int t3 = (unsigned short)h3 | ((unsigned)(unsigned short)f2bf(v.w - bf2f(h3)) << 16);
        *(int2*)&xil[T]     = make_int2(t0, t1);
        *(int2*)&xil[T + 2] = make_int2(t2, t3);
    }

    __syncthreads();

    // ================= gate pass: A and B interleaved =================
    float sgA = 0.f, sgB = 0.f;
    #pragma unroll 1
    for (int m = 0; m < 16; ++m) {
        int px = (wid << 8) + (m << 4) + r15;
        int rowbase = (px >> 5) * RS2 + (px & 31) + 1;
        int vA = rowbase + kgoff;
        int vB = rowbase + 2 * RS2;

        // sample A reads
        int TA0 = xil[vA];           int TA1 = xil[vA + 1];
        int TA2 = xil[vA + 2];       int TA3 = xil[vA + RS2];
        int TA4 = xil[vA + RS2 + 1]; int TA5 = xil[vA + RS2 + 2];
        int TA6 = xil[vA + 2 * RS2]; int TA7 = xil[vA + 2 * RS2 + 1];
        int UA0 = xil[vB + 2];       int UA1 = xil[vB + 2 + CS];
        int UA2 = xil[vB + 2 + 2 * CS];
        // sample B reads (independent chain)
        int wA = vA + NTX, wB = vB + NTX;
        int TB0 = xil[wA];           int TB1 = xil[wA + 1];
        int TB2 = xil[wA + 2];       int TB3 = xil[wA + RS2];
        int TB4 = xil[wA + RS2 + 1]; int TB5 = xil[wA + RS2 + 2];
        int TB6 = xil[wA + 2 * RS2]; int TB7 = xil[wA + 2 * RS2 + 1];
        int UB0 = xil[wB + 2];       int UB1 = xil[wB + 2 + CS];
        int UB2 = xil[wB + 2 + 2 * CS];

        int XA0 = k3 ? UA0 : TA0;  int XA1 = k3 ? UA1 : TA1;  int XA2 = k3 ? UA2 : TA2;
        int XB0 = k3 ? UB0 : TB0;  int XB1 = k3 ? UB1 : TB1;  int XB2 = k3 ? UB2 : TB2;

        int4v ahdA = { (int)__builtin_amdgcn_perm(XA1, XA0, 0x05040100u),
                       (int)__builtin_amdgcn_perm(TA3, XA2, 0x05040100u),
                       (int)__builtin_amdgcn_perm(TA5, TA4, 0x05040100u),
                       (int)__builtin_amdgcn_perm(TA7, TA6, 0x05040100u) };
        int4v aldA = { (int)__builtin_amdgcn_perm(XA1, XA0, 0x07060302u),
                       (int)__builtin_amdgcn_perm(TA3, XA2, 0x07060302u),
                       (int)__builtin_amdgcn_perm(TA5, TA4, 0x07060302u),
                       (int)__builtin_amdgcn_perm(TA7, TA6, 0x07060302u) };
        int4v ahdB = { (int)__builtin_amdgcn_perm(XB1, XB0, 0x05040100u),
                       (int)__builtin_amdgcn_perm(TB3, XB2, 0x05040100u),
                       (int)__builtin_amdgcn_perm(TB5, TB4, 0x05040100u),
                       (int)__builtin_amdgcn_perm(TB7, TB6, 0x05040100u) };
        int4v aldB = { (int)__builtin_amdgcn_perm(XB1, XB0, 0x07060302u),
                       (int)__builtin_amdgcn_perm(TB3, XB2, 0x07060302u),
                       (int)__builtin_amdgcn_perm(TB5, TB4, 0x07060302u),
                       (int)__builtin_amdgcn_perm(TB7, TB6, 0x07060302u) };
        bf16x8 ahA = __builtin_bit_cast(bf16x8, ahdA);
        bf16x8 alA = __builtin_bit_cast(bf16x8, aldA);
        bf16x8 ahB = __builtin_bit_cast(bf16x8, ahdB);
        bf16x8 alB = __builtin_bit_cast(bf16x8, aldB);

        f32x4 dA = {0.f, 0.f, 0.f, 0.f};
        f32x4 dB = {0.f, 0.f, 0.f, 0.f};
        dA = __builtin_amdgcn_mfma_f32_16x16x32_bf16(alA, gbh, dA, 0, 0, 0);
        dB = __builtin_amdgcn_mfma_f32_16x16x32_bf16(alB, gbh, dB, 0, 0, 0);
        dA = __builtin_amdgcn_mfma_f32_16x16x32_bf16(ahA, gbl, dA, 0, 0, 0);
        dB = __builtin_amdgcn_mfma_f32_16x16x32_bf16(ahB, gbl, dB, 0, 0, 0);
        dA = __builtin_amdgcn_mfma_f32_16x16x32_bf16(ahA, gbh, dA, 0, 0, 0);
        dB = __builtin_amdgcn_mfma_f32_16x16x32_bf16(ahB, gbh, dB, 0, 0, 0);
        sgA += fmaxf(dA[0] + gb, 0.f) + fmaxf(dA[1] + gb, 0.f) +
               fmaxf(dA[2] + gb, 0.f) + fmaxf(dA[3] + gb, 0.f);
        sgB += fmaxf(dB[0] + gb, 0.f) + fmaxf(dB[1] + gb, 0.f) +
               fmaxf(dB[2] + gb, 0.f) + fmaxf(dB[3] + gb, 0.f);
    }
    {
        float vA2 = sgA, vB2 = sgB;
        vA2 += __shfl_xor(vA2, 16); vA2 += __shfl_xor(vA2, 32);
        vB2 += __shfl_xor(vB2, 16); vB2 += __shfl_xor(vB2, 32);
        if (lane < 16) { red2[wid][lane] = vA2; red2[wid][lane + 32] = vB2; }
    }
    __syncthreads();
    if (t < 32) {
        int s = t >> 4, c = t & 15;
        int col = s * 32 + c;
        pg[s][c] = (red2[0][col] + red2[1][col] + red2[2][col] + red2[3][col])
                   * (1.f / 1024.f);
    }
    __syncthreads();

    // ---- gate linear + softmax + argmax: lanes 0..15 (8 per sample) ----
    if (t < 16) {
        int s = t >> 3, ee = t & 7;
        float acc = glb[ee];
        #pragma unroll
        for (int c = 0; c < GCH; ++c) acc += pg[s][c] * glw[ee * GCH + c];
        float m = acc;
        #pragma unroll
        for (int o = 1; o < NE; o <<= 1) m = fmaxf(m, __shfl_xor(m, o));
        float ex = expf(acc - m);
        float ssum = ex;
        #pragma unroll
        for (int o = 1; o < NE; o <<= 1) ssum += __shfl_xor(ssum, o);
        out_w[(size_t)(s ? bB : bA) * NE + ee] = ex / ssum;
        float mv = acc; int mi = ee;
        #pragma unroll
        for (int o = 1; o < NE; o <<= 1) {
            float ov = __shfl_xor(mv, o);
            int   oi = __shfl_xor(mi, o);
            if (ov > mv || (ov == mv && oi < mi)) { mv = ov; mi = oi; }
        }
        if (ee == 0) s_best[s] = mi;
    }
    __syncthreads();
    const int eA = __builtin_amdgcn_readfirstlane(s_best[0]);
    const int eB = __builtin_amdgcn_readfirstlane(s_best[1]);

    // ================= expert pass: A and B interleaved =================
    const float* ewpA = ecw + (size_t)eA * (ECH * 27);
    const float* ewpB = ecw + (size_t)eB * (ECH * 27);
    const float* ebpA = ecb + (size_t)eA * ECH;
    const float* ebpB = ecb + (size_t)eB * ECH;

    bf16x8 bA0, bA1, bB0, bB1;
    #pragma unroll
    for (int r = 0; r < 8; ++r) {
        float wa0 = 0.f, wa1 = 0.f, wb0 = 0.f, wb1 = 0.f;
        if (kg < 3) {
            wa0 = ewpA[r15 * 27 + kg * 9 + r];
            wa1 = ewpA[(16 + r15) * 27 + kg * 9 + r];
            wb0 = ewpB[r15 * 27 + kg * 9 + r];
            wb1 = ewpB[(16 + r15) * 27 + kg * 9 + r];
        } else if (r < 3) {
            wa0 = ewpA[r15 * 27 + r * 9 + 8];
            wa1 = ewpA[(16 + r15) * 27 + r * 9 + 8];
            wb0 = ewpB[r15 * 27 + r * 9 + 8];
            wb1 = ewpB[(16 + r15) * 27 + r * 9 + 8];
        }
        bA0[r] = f2bf(wa0); bA1[r] = f2bf(wa1);
        bB0[r] = f2bf(wb0); bB1[r] = f2bf(wb1);
    }
    const float c0A = ebpA[r15], c1A = ebpA[16 + r15];
    const float c0B = ebpB[r15], c1B = ebpB[16 + r15];

    float s0A = 0.f, s1A = 0.f, s0B = 0.f, s1B = 0.f;
    #pragma unroll 1
    for (int m = 0; m < 16; ++m) {
        int px = (wid << 8) + (m << 4) + r15;
        int rowbase = (px >> 5) * RS2 + (px & 31) + 1;
        int vA = rowbase + kgoff;
        int vB = rowbase + 2 * RS2;
        int TA0 = xil[vA];           int TA1 = xil[vA + 1];
        int TA2 = xil[vA + 2];       int TA3 = xil[vA + RS2];
        int TA4 = xil[vA + RS2 + 1]; int TA5 = xil[vA + RS2 + 2];
        int TA6 = xil[vA + 2 * RS2]; int TA7 = xil[vA + 2 * RS2 + 1];
        int UA0 = xil[vB + 2];       int UA1 = xil[vB + 2 + CS];
        int UA2 = xil[vB + 2 + 2 * CS];
        int wA = vA + NTX, wB = vB + NTX;
        int TB0 = xil[wA];           int TB1 = xil[wA + 1];
        int TB2 = xil[wA + 2];       int TB3 = xil[wA + RS2];
        int TB4 = xil[wA + RS2 + 1]; int TB5 = xil[wA + RS2 + 2];
        int TB6 = xil[wA + 2 * RS2]; int TB7 = xil[wA + 2 * RS2 + 1];
        int UB0 = xil[wB + 2];       int UB1 = xil[wB + 2 + CS];
        int UB2 = xil[wB + 2 + 2 * CS];

        int XA0 = k3 ? UA0 : TA0;  int XA1 = k3 ? UA1 : TA1;  int XA2 = k3 ? UA2 : TA2;
        int XB0 = k3 ? UB0 : TB0;  int XB1 = k3 ? UB1 : TB1;  int XB2 = k3 ? UB2 : TB2;

        int4v ahdA = { (int)__builtin_amdgcn_perm(XA1, XA0, 0x05040100u),
                       (int)__builtin_amdgcn_perm(TA3, XA2, 0x05040100u),
                       (int)__builtin_amdgcn_perm(TA5, TA4, 0x05040100u),
                       (int)__builtin_amdgcn_perm(TA7, TA6, 0x05040100u) };
        int4v ahdB = { (int)__builtin_amdgcn_perm(XB1, XB0, 0x05040100u),
                       (int)__builtin_amdgcn_perm(TB3, XB2, 0x05040100u),
                       (int)__builtin_amdgcn_perm(TB5, TB4, 0x05040100u),
                       (int)__builtin_amdgcn_perm(TB7, TB6, 0x05040100u) };
        bf16x8 aA = __builtin_bit_cast(bf16x8, ahdA);
        bf16x8 aB = __builtin_bit_cast(bf16x8, ahdB);
        f32x4 z = {0.f, 0.f, 0.f, 0.f};
        f32x4 d0A = __builtin_amdgcn_mfma_f32_16x16x32_bf16(aA, bA0, z, 0, 0, 0);
        f32x4 d0B = __builtin_amdgcn_mfma_f32_16x16x32_bf16(aB, bB0, z, 0, 0, 0);
        f32x4 d1A = __builtin_amdgcn_mfma_f32_16x16x32_bf16(aA, bA1, z, 0, 0, 0);
        f32x4 d1B = __builtin_amdgcn_mfma_f32_16x16x32_bf16(aB, bB1, z, 0, 0, 0);
        s0A += fmaxf(d0A[0] + c0A, 0.f) + fmaxf(d0A[1] + c0A, 0.f) +
               fmaxf(d0A[2] + c0A, 0.f) + fmaxf(d0A[3] + c0A, 0.f);
        s1A += fmaxf(d1A[0] + c1A, 0.f) + fmaxf(d1A[1] + c1A, 0.f) +
               fmaxf(d1A[2] + c1A, 0.f) + fmaxf(d1A[3] + c1A, 0.f);
        s0B += fmaxf(d0B[0] + c0B, 0.f) + fmaxf(d0B[1] + c0B, 0.f) +
               fmaxf(d0B[2] + c0B, 0.f) + fmaxf(d0B[3] + c0B, 0.f);
        s1B += fmaxf(d1B[0] + c1B, 0.f) + fmaxf(d1B[1] + c1B, 0.f) +
               fmaxf(d1B[2] + c1B, 0.f) + fmaxf(d1B[3] + c1B, 0.f);
    }
    {
        float v0A = s0A, v1A = s1A, v0B = s0B, v1B = s1B;
        v0A += __shfl_xor(v0A, 16); v0A += __shfl_xor(v0A, 32);
        v1A += __shfl_xor(v1A, 16); v1A += __shfl_xor(v1A, 32);
        v0B += __shfl_xor(v0B, 16); v0B += __shfl_xor(v0B, 32);
        v1B += __shfl_xor(v1B, 16); v1B += __shfl_xor(v1B, 32);
        if (lane < 16) {
            red2[wid][lane]      = v0A;
            red2[wid][lane + 16] = v1A;
            red2[wid][lane + 32] = v0B;
            red2[wid][lane + 48] = v1B;
        }
    }
    __syncthreads();
    if (t < 64) {
        pe[t >> 5][t & 31] = (red2[0][t] + red2[1][t] + red2[2][t] + red2[3][t])
                             * (1.f / 1024.f);
    }
    __syncthreads();

    // ---- expert linear: 2 x 100 outputs ----
    if (t < 200) {
        int s = (t >= 100) ? 1 : 0;
        int c = t - s * 100;
        int es = s ? eB : eA;
        const float* lw = elw + ((size_t)es * NC + c) * ECH;
        float acc = elb[es * NC + c];
        #pragma unroll
        for (int ch = 0; ch < ECH; ++ch) acc += pe[s][ch] * lw[ch];
        out_final[(size_t)(s ? bB : bA) * NC + c] = acc;
    }
}

extern "C" void kernel_launch(void* const* d_in, const int* in_sizes, int n_in,
                              void* d_out, int out_size, void* d_ws, size_t ws_size,
                              hipStream_t stream) {
    const float* x   = (const float*)d_in[0];
    const float* gcw = (const float*)d_in[1];
    const float* gcb = (const float*)d_in[2];
    const float* glw = (const float*)d_in[3];
    const float* glb = (const float*)d_in[4];
    const float* ecw = (const float*)d_in[5];
    const float* ecb = (const float*)d_in[6];
    const float* elw = (const float*)d_in[7];
    const float* elb = (const float*)d_in[8];

    float* out_final = (float*)d_out;             // [1024,100]
    float* out_w     = (float*)d_out + NB * NC;   // [1024,8]

    hipLaunchKernelGGL(moe_fused_kernel, dim3(NB / 2), dim3(256), 0, stream,
                       x, gcw, gcb, glw, glb, ecw, ecb, elw, elb,
                       out_final, out_w);
}

// Round 20
// 19.838 us; speedup vs baseline: 1.1783x; 1.1783x over previous
//
#include <hip/hip_runtime.h>
#include <math.h>

#define NB 1024
#define IC 3
#define HW 32
#define GCH 16
#define ECH 32
#define NE 8
#define NC 100

#define CS 38            // plane (ci) stride in texels
#define RS2 114          // row stride (3 planes interleaved per row)
#define NTX 3876         // 34 rows * 114

typedef __attribute__((ext_vector_type(8))) short bf16x8;
typedef __attribute__((ext_vector_type(4))) int   int4v;
typedef __attribute__((ext_vector_type(4))) float f32x4;

__device__ inline short f2bf(float f) {   // RNE fp32->bf16
    unsigned u = __float_as_uint(f);
    unsigned r = (u + 0x7FFF + ((u >> 16) & 1)) >> 16;
    return (short)r;
}
__device__ inline float bf2f(short h) {
    return __uint_as_float(((unsigned)(unsigned short)h) << 16);
}

// Best configuration (r18, 19.80 us): one sample per block, 256 threads.
// Layout [row][ci][col] (row stride 114, plane stride 38): each lane's 8
// conv taps sit at wave-uniform immediate offsets {0,1,2,114,115,116,228,229}
// from vA = rowbase + kg*38. k-relabel: kg0..2 = taps 0..7 of plane kg;
// kg3 = leftover (ky2,kx2) taps at vB+{2,40,78}; pads k>=27 have B=0 so
// kg3's junk slots are harmless. A/B share the k-map (permutation
// self-cancels in the dot product).
// Gate: hi/lo bf16 split (3 MFMAs) -> ~1e-5 logit error, argmax-exact.
// Expert: hi-only (2 MFMAs), absmax 0.0078125 (threshold 0.0248).
// Session ladder: 59.8 (fp32 VALU baseline) -> 40.2 (ds_read_b128 tiles)
// -> 28.2 (expert MFMA) -> 21.8 (gate MFMA hi/lo) -> 19.8 (texel layout).
// Probed and falsified at this plateau: 512-thr blocks (+4.4us), border-only
// zeroing (+1.0), imm-offset merge (null), 2-sample ILP (+3.6) -> remaining
// gap to the ~6.4us issue floor is distributed latency/barrier/serial cost.
__global__ __launch_bounds__(256) void moe_fused_kernel(
    const float* __restrict__ x,     // [1024,3,32,32]
    const float* __restrict__ gcw,   // [16,3,3,3]
    const float* __restrict__ gcb,   // [16]
    const float* __restrict__ glw,   // [8,16]
    const float* __restrict__ glb,   // [8]
    const float* __restrict__ ecw,   // [8,32,3,3,3]
    const float* __restrict__ ecb,   // [8,32]
    const float* __restrict__ elw,   // [8,100,32]
    const float* __restrict__ elb,   // [8,100]
    float* __restrict__ out_final,   // [1024,100]
    float* __restrict__ out_w)       // [1024,8]
{
    __shared__ __align__(16) int xil[NTX];   // 15.5 KB interleaved texels
    __shared__ float red2[4][32];
    __shared__ float pg[GCH];
    __shared__ float pe[ECH];
    __shared__ int s_best;

    const int t = threadIdx.x;
    const int b = blockIdx.x;
    const int lane = t & 63;
    const int wid = t >> 6;
    const int r15 = lane & 15;
    const int kg = lane >> 4;
    const bool k3 = (kg == 3);
    const int kgoff = k3 ? 0 : kg * CS;   // kg3 aliases kg0 (broadcast, junk)

    // ---- zero all texels (borders stay zero) ----
    for (int i = t; i < NTX / 4; i += 256) ((int4*)xil)[i] = make_int4(0, 0, 0, 0);

    // ---- gate B-fragments (hi+lo) under the k-map ----
    bf16x8 gbh, gbl;
    #pragma unroll
    for (int r = 0; r < 8; ++r) {
        float w = 0.f;
        if (kg < 3) w = gcw[r15 * 27 + kg * 9 + r];
        else if (r < 3) w = gcw[r15 * 27 + r * 9 + 8];
        short h = f2bf(w);
        gbh[r] = h;
        gbl[r] = f2bf(w - bf2f(h));
    }
    const float gb = gcb[r15];

    __syncthreads();

    // ---- stage x -> interleaved texels: (row+1)*114 + ci*38 + col+2 ----
    const float* xb = x + (size_t)b * (IC * HW * HW);
    #pragma unroll
    for (int i3 = 0; i3 < 3; ++i3) {
        int i = t + i3 * 256;
        float4 v = ((const float4*)xb)[i];
        int ci = i >> 8, rem = i & 255, row = rem >> 3, x4 = (rem & 7) << 2;
        int T = (row + 1) * RS2 + ci * CS + x4 + 2;   // even -> b64 aligned
        short h0 = f2bf(v.x), h1 = f2bf(v.y), h2 = f2bf(v.z), h3 = f2bf(v.w);
        int t0 = (unsigned short)h0 | ((unsigned)(unsigned short)f2bf(v.x - bf2f(h0)) << 16);
        int t1 = (unsigned short)h1 | ((unsigned)(unsigned short)f2bf(v.y - bf2f(h1)) << 16);
        int t2 = (unsigned short)h2 | ((unsigned)(unsigned short)f2bf(v.z - bf2f(h2)) << 16);
        int t3 = (unsigned short)h3 | ((unsigned)(unsigned short)f2bf(v.w - bf2f(h3)) << 16);
        *(int2*)&xil[T]     = make_int2(t0, t1);
        *(int2*)&xil[T + 2] = make_int2(t2, t3);
    }

    __syncthreads();

    // ================= gate pass (hi/lo MFMA) =================
    float sg = 0.f;
    #pragma unroll 2
    for (int m = 0; m < 16; ++m) {
        int px = (wid << 8) + (m << 4) + r15;
        int rowbase = (px >> 5) * RS2 + (px & 31) + 1;
        int vA = rowbase + kgoff;
        int vB = rowbase + 2 * RS2;
        int T0 = xil[vA];           int T1 = xil[vA + 1];
        int T2 = xil[vA + 2];       int T3 = xil[vA + RS2];
        int T4 = xil[vA + RS2 + 1]; int T5 = xil[vA + RS2 + 2];
        int T6 = xil[vA + 2 * RS2]; int T7 = xil[vA + 2 * RS2 + 1];
        int U0 = xil[vB + 2];       int U1 = xil[vB + 2 + CS];
        int U2 = xil[vB + 2 + 2 * CS];
        int X0 = k3 ? U0 : T0;
        int X1 = k3 ? U1 : T1;
        int X2 = k3 ? U2 : T2;
        int4v ahd = { (int)__builtin_amdgcn_perm(X1, X0, 0x05040100u),
                      (int)__builtin_amdgcn_perm(T3, X2, 0x05040100u),
                      (int)__builtin_amdgcn_perm(T5, T4, 0x05040100u),
                      (int)__builtin_amdgcn_perm(T7, T6, 0x05040100u) };
        int4v ald = { (int)__builtin_amdgcn_perm(X1, X0, 0x07060302u),
                      (int)__builtin_amdgcn_perm(T3, X2, 0x07060302u),
                      (int)__builtin_amdgcn_perm(T5, T4, 0x07060302u),
                      (int)__builtin_amdgcn_perm(T7, T6, 0x07060302u) };
        bf16x8 ah = __builtin_bit_cast(bf16x8, ahd);
        bf16x8 al = __builtin_bit_cast(bf16x8, ald);
        f32x4 d = {0.f, 0.f, 0.f, 0.f};
        d = __builtin_amdgcn_mfma_f32_16x16x32_bf16(al, gbh, d, 0, 0, 0);
        d = __builtin_amdgcn_mfma_f32_16x16x32_bf16(ah, gbl, d, 0, 0, 0);
        d = __builtin_amdgcn_mfma_f32_16x16x32_bf16(ah, gbh, d, 0, 0, 0);
        sg += fmaxf(d[0] + gb, 0.f) + fmaxf(d[1] + gb, 0.f) +
              fmaxf(d[2] + gb, 0.f) + fmaxf(d[3] + gb, 0.f);
    }
    {
        float v = sg;
        v += __shfl_xor(v, 16);
        v += __shfl_xor(v, 32);
        if (lane < 16) red2[wid][lane] = v;
    }
    __syncthreads();
    if (t < GCH)
        pg[t] = (red2[0][t] + red2[1][t] + red2[2][t] + red2[3][t]) * (1.f / 1024.f);
    __syncthreads();

    // ---- gate linear + softmax + argmax (lanes 0..7) ----
    if (t < NE) {
        float acc = glb[t];
        #pragma unroll
        for (int c = 0; c < GCH; ++c) acc += pg[c] * glw[t * GCH + c];
        float m = acc;
        #pragma unroll
        for (int o = 1; o < NE; o <<= 1) m = fmaxf(m, __shfl_xor(m, o));
        float ex = expf(acc - m);
        float s = ex;
        #pragma unroll
        for (int o = 1; o < NE; o <<= 1) s += __shfl_xor(s, o);
        out_w[(size_t)b * NE + t] = ex / s;
        float mv = acc; int mi = t;
        #pragma unroll
        for (int o = 1; o < NE; o <<= 1) {
            float ov = __shfl_xor(mv, o);
            int   oi = __shfl_xor(mi, o);
            if (ov > mv || (ov == mv && oi < mi)) { mv = ov; mi = oi; }
        }
        if (t == 0) s_best = mi;
    }
    __syncthreads();
    const int e = __builtin_amdgcn_readfirstlane(s_best);

    // ================= expert pass (hi-only MFMA) =================
    const float* ewp = ecw + (size_t)e * (ECH * 27);
    const float* ebp = ecb + (size_t)e * ECH;

    bf16x8 bfr0, bfr1;
    #pragma unroll
    for (int r = 0; r < 8; ++r) {
        float w0 = 0.f, w1 = 0.f;
        if (kg < 3) {
            w0 = ewp[r15 * 27 + kg * 9 + r];
            w1 = ewp[(16 + r15) * 27 + kg * 9 + r];
        } else if (r < 3) {
            w0 = ewp[r15 * 27 + r * 9 + 8];
            w1 = ewp[(16 + r15) * 27 + r * 9 + 8];
        }
        bfr0[r] = f2bf(w0);
        bfr1[r] = f2bf(w1);
    }
    const float b0 = ebp[r15];
    const float b1 = ebp[16 + r15];

    float s0 = 0.f, s1 = 0.f;
    #pragma unroll 2
    for (int m = 0; m < 16; ++m) {
        int px = (wid << 8) + (m << 4) + r15;
        int rowbase = (px >> 5) * RS2 + (px & 31) + 1;
        int vA = rowbase + kgoff;
        int vB = rowbase + 2 * RS2;
        int T0 = xil[vA];           int T1 = xil[vA + 1];
        int T2 = xil[vA + 2];       int T3 = xil[vA + RS2];
        int T4 = xil[vA + RS2 + 1]; int T5 = xil[vA + RS2 + 2];
        int T6 = xil[vA + 2 * RS2]; int T7 = xil[vA + 2 * RS2 + 1];
        int U0 = xil[vB + 2];       int U1 = xil[vB + 2 + CS];
        int U2 = xil[vB + 2 + 2 * CS];
        int X0 = k3 ? U0 : T0;
        int X1 = k3 ? U1 : T1;
        int X2 = k3 ? U2 : T2;
        int4v ahd = { (int)__builtin_amdgcn_perm(X1, X0, 0x05040100u),
                      (int)__builtin_amdgcn_perm(T3, X2, 0x05040100u),
                      (int)__builtin_amdgcn_perm(T5, T4, 0x05040100u),
                      (int)__builtin_amdgcn_perm(T7, T6, 0x05040100u) };
        bf16x8 a = __builtin_bit_cast(bf16x8, ahd);
        f32x4 z = {0.f, 0.f, 0.f, 0.f};
        f32x4 d0 = __builtin_amdgcn_mfma_f32_16x16x32_bf16(a, bfr0, z, 0, 0, 0);
        f32x4 d1 = __builtin_amdgcn_mfma_f32_16x16x32_bf16(a, bfr1, z, 0, 0, 0);
        s0 += fmaxf(d0[0] + b0, 0.f) + fmaxf(d0[1] + b0, 0.f) +
              fmaxf(d0[2] + b0, 0.f) + fmaxf(d0[3] + b0, 0.f);
        s1 += fmaxf(d1[0] + b1, 0.f) + fmaxf(d1[1] + b1, 0.f) +
              fmaxf(d1[2] + b1, 0.f) + fmaxf(d1[3] + b1, 0.f);
    }
    {
        float v0 = s0, v1 = s1;
        v0 += __shfl_xor(v0, 16); v0 += __shfl_xor(v0, 32);
        v1 += __shfl_xor(v1, 16); v1 += __shfl_xor(v1, 32);
        if (lane < 16) { red2[wid][lane] = v0; red2[wid][lane + 16] = v1; }
    }
    __syncthreads();
    if (t < ECH)
        pe[t] = (red2[0][t] + red2[1][t] + red2[2][t] + red2[3][t]) * (1.f / 1024.f);
    __syncthreads();

    // ---- expert linear: 100 outputs ----
    if (t < NC) {
        const float* lw = elw + ((size_t)e * NC + t) * ECH;
        float acc = elb[e * NC + t];
        #pragma unroll
        for (int c = 0; c < ECH; ++c) acc += pe[c] * lw[c];
        out_final[(size_t)b * NC + t] = acc;
    }
}

extern "C" void kernel_launch(void* const* d_in, const int* in_sizes, int n_in,
                              void* d_out, int out_size, void* d_ws, size_t ws_size,
                              hipStream_t stream) {
    const float* x   = (const float*)d_in[0];
    const float* gcw = (const float*)d_in[1];
    const float* gcb = (const float*)d_in[2];
    const float* glw = (const float*)d_in[3];
    const float* glb = (const float*)d_in[4];
    const float* ecw = (const float*)d_in[5];
    const float* ecb = (const float*)d_in[6];
    const float* elw = (const float*)d_in[7];
    const float* elb = (const float*)d_in[8];

    float* out_final = (float*)d_out;             // [1024,100]
    float* out_w     = (float*)d_out + NB * NC;   // [1024,8]

    hipLaunchKernelGGL(moe_fused_kernel, dim3(NB), dim3(256), 0, stream,
                       x, gcw, gcb, glw, glb, ecw, ecb, elw, elb,
                       out_final, out_w);
}

// Round 21
// 19.825 us; speedup vs baseline: 1.1790x; 1.0006x over previous
//
#include <hip/hip_runtime.h>
#include <math.h>

#define NB 1024
#define IC 3
#define HW 32
#define GCH 16
#define ECH 32
#define NE 8
#define NC 100

#define CS 38            // plane (ci) stride in texels
#define RS2 114          // row stride (3 planes interleaved per row)
#define NTX 3876         // 34 rows * 114

typedef __attribute__((ext_vector_type(8))) short bf16x8;
typedef __attribute__((ext_vector_type(4))) int   int4v;
typedef __attribute__((ext_vector_type(4))) float f32x4;

__device__ inline short f2bf(float f) {   // RNE fp32->bf16
    unsigned u = __float_as_uint(f);
    unsigned r = (u + 0x7FFF + ((u >> 16) & 1)) >> 16;
    return (short)r;
}
__device__ inline float bf2f(short h) {
    return __uint_as_float(((unsigned)(unsigned short)h) << 16);
}

// Best configuration (r18, 19.80 us): one sample per block, 256 threads.
// Layout [row][ci][col] (row stride 114, plane stride 38): each lane's 8
// conv taps sit at wave-uniform immediate offsets {0,1,2,114,115,116,228,229}
// from vA = rowbase + kg*38. k-relabel: kg0..2 = taps 0..7 of plane kg;
// kg3 = leftover (ky2,kx2) taps at vB+{2,40,78}; pads k>=27 have B=0 so
// kg3's junk slots are harmless. A/B share the k-map (permutation
// self-cancels in the dot product).
// Gate: hi/lo bf16 split (3 MFMAs) -> ~1e-5 logit error, argmax-exact.
// Expert: hi-only (2 MFMAs), absmax 0.0078125 (threshold 0.0248).
// Session ladder: 59.8 (fp32 VALU baseline) -> 40.2 (ds_read_b128 tiles)
// -> 28.2 (expert MFMA) -> 21.8 (gate MFMA hi/lo) -> 19.8 (texel layout).
// Probed and falsified at this plateau: 512-thr blocks (+4.4us), border-only
// zeroing (+1.0), imm-offset merge (null), 2-sample ILP (+3.6) -> remaining
// gap to the ~6.4us issue floor is distributed latency/barrier/serial cost.
__global__ __launch_bounds__(256) void moe_fused_kernel(
    const float* __restrict__ x,     // [1024,3,32,32]
    const float* __restrict__ gcw,   // [16,3,3,3]
    const float* __restrict__ gcb,   // [16]
    const float* __restrict__ glw,   // [8,16]
    const float* __restrict__ glb,   // [8]
    const float* __restrict__ ecw,   // [8,32,3,3,3]
    const float* __restrict__ ecb,   // [8,32]
    const float* __restrict__ elw,   // [8,100,32]
    const float* __restrict__ elb,   // [8,100]
    float* __restrict__ out_final,   // [1024,100]
    float* __restrict__ out_w)       // [1024,8]
{
    __shared__ __align__(16) int xil[NTX];   // 15.5 KB interleaved texels
    __shared__ float red2[4][32];
    __shared__ float pg[GCH];
    __shared__ float pe[ECH];
    __shared__ int s_best;

    const int t = threadIdx.x;
    const int b = blockIdx.x;
    const int lane = t & 63;
    const int wid = t >> 6;
    const int r15 = lane & 15;
    const int kg = lane >> 4;
    const bool k3 = (kg == 3);
    const int kgoff = k3 ? 0 : kg * CS;   // kg3 aliases kg0 (broadcast, junk)

    // ---- zero all texels (borders stay zero) ----
    for (int i = t; i < NTX / 4; i += 256) ((int4*)xil)[i] = make_int4(0, 0, 0, 0);

    // ---- gate B-fragments (hi+lo) under the k-map ----
    bf16x8 gbh, gbl;
    #pragma unroll
    for (int r = 0; r < 8; ++r) {
        float w = 0.f;
        if (kg < 3) w = gcw[r15 * 27 + kg * 9 + r];
        else if (r < 3) w = gcw[r15 * 27 + r * 9 + 8];
        short h = f2bf(w);
        gbh[r] = h;
        gbl[r] = f2bf(w - bf2f(h));
    }
    const float gb = gcb[r15];

    __syncthreads();

    // ---- stage x -> interleaved texels: (row+1)*114 + ci*38 + col+2 ----
    const float* xb = x + (size_t)b * (IC * HW * HW);
    #pragma unroll
    for (int i3 = 0; i3 < 3; ++i3) {
        int i = t + i3 * 256;
        float4 v = ((const float4*)xb)[i];
        int ci = i >> 8, rem = i & 255, row = rem >> 3, x4 = (rem & 7) << 2;
        int T = (row + 1) * RS2 + ci * CS + x4 + 2;   // even -> b64 aligned
        short h0 = f2bf(v.x), h1 = f2bf(v.y), h2 = f2bf(v.z), h3 = f2bf(v.w);
        int t0 = (unsigned short)h0 | ((unsigned)(unsigned short)f2bf(v.x - bf2f(h0)) << 16);
        int t1 = (unsigned short)h1 | ((unsigned)(unsigned short)f2bf(v.y - bf2f(h1)) << 16);
        int t2 = (unsigned short)h2 | ((unsigned)(unsigned short)f2bf(v.z - bf2f(h2)) << 16);
        int t3 = (unsigned short)h3 | ((unsigned)(unsigned short)f2bf(v.w - bf2f(h3)) << 16);
        *(int2*)&xil[T]     = make_int2(t0, t1);
        *(int2*)&xil[T + 2] = make_int2(t2, t3);
    }

    __syncthreads();

    // ================= gate pass (hi/lo MFMA) =================
    float sg = 0.f;
    #pragma unroll 2
    for (int m = 0; m < 16; ++m) {
        int px = (wid << 8) + (m << 4) + r15;
        int rowbase = (px >> 5) * RS2 + (px & 31) + 1;
        int vA = rowbase + kgoff;
        int vB = rowbase + 2 * RS2;
        int T0 = xil[vA];           int T1 = xil[vA + 1];
        int T2 = xil[vA + 2];       int T3 = xil[vA + RS2];
        int T4 = xil[vA + RS2 + 1]; int T5 = xil[vA + RS2 + 2];
        int T6 = xil[vA + 2 * RS2]; int T7 = xil[vA + 2 * RS2 + 1];
        int U0 = xil[vB + 2];       int U1 = xil[vB + 2 + CS];
        int U2 = xil[vB + 2 + 2 * CS];
        int X0 = k3 ? U0 : T0;
        int X1 = k3 ? U1 : T1;
        int X2 = k3 ? U2 : T2;
        int4v ahd = { (int)__builtin_amdgcn_perm(X1, X0, 0x05040100u),
                      (int)__builtin_amdgcn_perm(T3, X2, 0x05040100u),
                      (int)__builtin_amdgcn_perm(T5, T4, 0x05040100u),
                      (int)__builtin_amdgcn_perm(T7, T6, 0x05040100u) };
        int4v ald = { (int)__builtin_amdgcn_perm(X1, X0, 0x07060302u),
                      (int)__builtin_amdgcn_perm(T3, X2, 0x07060302u),
                      (int)__builtin_amdgcn_perm(T5, T4, 0x07060302u),
                      (int)__builtin_amdgcn_perm(T7, T6, 0x07060302u) };
        bf16x8 ah = __builtin_bit_cast(bf16x8, ahd);
        bf16x8 al = __builtin_bit_cast(bf16x8, ald);
        f32x4 d = {0.f, 0.f, 0.f, 0.f};
        d = __builtin_amdgcn_mfma_f32_16x16x32_bf16(al, gbh, d, 0, 0, 0);
        d = __builtin_amdgcn_mfma_f32_16x16x32_bf16(ah, gbl, d, 0, 0, 0);
        d = __builtin_amdgcn_mfma_f32_16x16x32_bf16(ah, gbh, d, 0, 0, 0);
        sg += fmaxf(d[0] + gb, 0.f) + fmaxf(d[1] + gb, 0.f) +
              fmaxf(d[2] + gb, 0.f) + fmaxf(d[3] + gb, 0.f);
    }
    {
        float v = sg;
        v += __shfl_xor(v, 16);
        v += __shfl_xor(v, 32);
        if (lane < 16) red2[wid][lane] = v;
    }
    __syncthreads();
    if (t < GCH)
        pg[t] = (red2[0][t] + red2[1][t] + red2[2][t] + red2[3][t]) * (1.f / 1024.f);
    __syncthreads();

    // ---- gate linear + softmax + argmax (lanes 0..7) ----
    if (t < NE) {
        float acc = glb[t];
        #pragma unroll
        for (int c = 0; c < GCH; ++c) acc += pg[c] * glw[t * GCH + c];
        float m = acc;
        #pragma unroll
        for (int o = 1; o < NE; o <<= 1) m = fmaxf(m, __shfl_xor(m, o));
        float ex = expf(acc - m);
        float s = ex;
        #pragma unroll
        for (int o = 1; o < NE; o <<= 1) s += __shfl_xor(s, o);
        out_w[(size_t)b * NE + t] = ex / s;
        float mv = acc; int mi = t;
        #pragma unroll
        for (int o = 1; o < NE; o <<= 1) {
            float ov = __shfl_xor(mv, o);
            int   oi = __shfl_xor(mi, o);
            if (ov > mv || (ov == mv && oi < mi)) { mv = ov; mi = oi; }
        }
        if (t == 0) s_best = mi;
    }
    __syncthreads();
    const int e = __builtin_amdgcn_readfirstlane(s_best);

    // ================= expert pass (hi-only MFMA) =================
    const float* ewp = ecw + (size_t)e * (ECH * 27);
    const float* ebp = ecb + (size_t)e * ECH;

    bf16x8 bfr0, bfr1;
    #pragma unroll
    for (int r = 0; r < 8; ++r) {
        float w0 = 0.f, w1 = 0.f;
        if (kg < 3) {
            w0 = ewp[r15 * 27 + kg * 9 + r];
            w1 = ewp[(16 + r15) * 27 + kg * 9 + r];
        } else if (r < 3) {
            w0 = ewp[r15 * 27 + r * 9 + 8];
            w1 = ewp[(16 + r15) * 27 + r * 9 + 8];
        }
        bfr0[r] = f2bf(w0);
        bfr1[r] = f2bf(w1);
    }
    const float b0 = ebp[r15];
    const float b1 = ebp[16 + r15];

    float s0 = 0.f, s1 = 0.f;
    #pragma unroll 2
    for (int m = 0; m < 16; ++m) {
        int px = (wid << 8) + (m << 4) + r15;
        int rowbase = (px >> 5) * RS2 + (px & 31) + 1;
        int vA = rowbase + kgoff;
        int vB = rowbase + 2 * RS2;
        int T0 = xil[vA];           int T1 = xil[vA + 1];
        int T2 = xil[vA + 2];       int T3 = xil[vA + RS2];
        int T4 = xil[vA + RS2 + 1]; int T5 = xil[vA + RS2 + 2];
        int T6 = xil[vA + 2 * RS2]; int T7 = xil[vA + 2 * RS2 + 1];
        int U0 = xil[vB + 2];       int U1 = xil[vB + 2 + CS];
        int U2 = xil[vB + 2 + 2 * CS];
        int X0 = k3 ? U0 : T0;
        int X1 = k3 ? U1 : T1;
        int X2 = k3 ? U2 : T2;
        int4v ahd = { (int)__builtin_amdgcn_perm(X1, X0, 0x05040100u),
                      (int)__builtin_amdgcn_perm(T3, X2, 0x05040100u),
                      (int)__builtin_amdgcn_perm(T5, T4, 0x05040100u),
                      (int)__builtin_amdgcn_perm(T7, T6, 0x05040100u) };
        bf16x8 a = __builtin_bit_cast(bf16x8, ahd);
        f32x4 z = {0.f, 0.f, 0.f, 0.f};
        f32x4 d0 = __builtin_amdgcn_mfma_f32_16x16x32_bf16(a, bfr0, z, 0, 0, 0);
        f32x4 d1 = __builtin_amdgcn_mfma_f32_16x16x32_bf16(a, bfr1, z, 0, 0, 0);
        s0 += fmaxf(d0[0] + b0, 0.f) + fmaxf(d0[1] + b0, 0.f) +
              fmaxf(d0[2] + b0, 0.f) + fmaxf(d0[3] + b0, 0.f);
        s1 += fmaxf(d1[0] + b1, 0.f) + fmaxf(d1[1] + b1, 0.f) +
              fmaxf(d1[2] + b1, 0.f) + fmaxf(d1[3] + b1, 0.f);
    }
    {
        float v0 = s0, v1 = s1;
        v0 += __shfl_xor(v0, 16); v0 += __shfl_xor(v0, 32);
        v1 += __shfl_xor(v1, 16); v1 += __shfl_xor(v1, 32);
        if (lane < 16) { red2[wid][lane] = v0; red2[wid][lane + 16] = v1; }
    }
    __syncthreads();
    if (t < ECH)
        pe[t] = (red2[0][t] + red2[1][t] + red2[2][t] + red2[3][t]) * (1.f / 1024.f);
    __syncthreads();

    // ---- expert linear: 100 outputs ----
    if (t < NC) {
        const float* lw = elw + ((size_t)e * NC + t) * ECH;
        float acc = elb[e * NC + t];
        #pragma unroll
        for (int c = 0; c < ECH; ++c) acc += pe[c] * lw[c];
        out_final[(size_t)b * NC + t] = acc;
    }
}

extern "C" void kernel_launch(void* const* d_in, const int* in_sizes, int n_in,
                              void* d_out, int out_size, void* d_ws, size_t ws_size,
                              hipStream_t stream) {
    const float* x   = (const float*)d_in[0];
    const float* gcw = (const float*)d_in[1];
    const float* gcb = (const float*)d_in[2];
    const float* glw = (const float*)d_in[3];
    const float* glb = (const float*)d_in[4];
    const float* ecw = (const float*)d_in[5];
    const float* ecb = (const float*)d_in[6];
    const float* elw = (const float*)d_in[7];
    const float* elb = (const float*)d_in[8];

    float* out_final = (float*)d_out;             // [1024,100]
    float* out_w     = (float*)d_out + NB * NC;   // [1024,8]

    hipLaunchKernelGGL(moe_fused_kernel, dim3(NB), dim3(256), 0, stream,
                       x, gcw, gcb, glw, glb, ecw, ecb, elw, elb,
                       out_final, out_w);
}